// Round 5
// baseline (136.919 us; speedup 1.0000x reference)
//
#include <hip/hip_runtime.h>

// B=16384 samples, F=256 features, T=512 trees, D=7 levels below root, C=4 outputs
#define BB 16384
#define FF 256
#define TT 512
#define DD 7

constexpr int S_   = 64;         // samples per block; one wave == one sample-group
constexpr int NT_  = 1024;       // 16 waves/block, grid=256 -> 1 block/CU
constexpr int NTG  = NT_ / S_;   // 16 tree-groups (one per wave)
constexpr int TPT  = TT / NTG;   // 32 trees per thread
constexpr int NP   = 16;         // concurrent tree chains per thread (ILP/MLP)
constexpr int NJ   = TPT / NP;   // 2 outer iterations

// Single dispatch (a second graph node costs ~25-40 us of wall time — measured
// rounds 1 vs 2/3/4). Nodes/biases/leaves gathered straight from L2: all 64
// lanes of a wave share one tree, so a level-l gather spans <= 2^l consecutive
// entries. The node and bias gathers are independent (both depend only on p),
// so the per-level dependent chain is max(node,bias) -> LDS x read.
// x rows live in LDS, XOR-swizzled (element f of row s at f ^ (s&31)) so
// bank = (f%32)^(s%32): shared-feature reads are conflict-free, no padding.
__global__ __launch_bounds__(NT_, 4)
void tree_traverse_kernel(const float* __restrict__ x,
                          const int*   __restrict__ root_nodes,
                          const float* __restrict__ root_biases,
                          const int*   __restrict__ nodes_flat,
                          const float* __restrict__ biases_flat,
                          const float* __restrict__ leaf_nodes,
                          float*       __restrict__ out)
{
    extern __shared__ float x_s[];   // 64 rows * 256 floats = 64 KB

    const int tid = threadIdx.x;
    const int s   = tid & (S_ - 1);    // lane's sample (wave covers all 64)
    const int tg  = tid >> 6;          // tree-group == wave id
    const int s0  = blockIdx.x * S_;

    // ---- stage x rows: float4 global loads, swizzled scalar LDS stores ----
    {
        const float4* xg = (const float4*)(x + (size_t)s0 * FF);
        const int r  = tid >> 4;       // row 0..63
        const int v  = tid & 15;       // 16 of 64 float4 per row
        const int rz = r & 31;
        float* row = x_s + (r << 8);
        #pragma unroll
        for (int c = 0; c < 4; ++c) {
            const float4 q = xg[r * (FF / 4) + v + 16 * c];
            const int f0 = (v + 16 * c) * 4;
            row[(f0 + 0) ^ rz] = q.x;
            row[(f0 + 1) ^ rz] = q.y;
            row[(f0 + 2) ^ rz] = q.z;
            row[(f0 + 3) ^ rz] = q.w;
        }
    }
    __syncthreads();

    const int   xb = s << 8;
    const int   sz = s & 31;
    const float4* leaf4 = (const float4*)leaf_nodes;
    float a0 = 0.f, a1 = 0.f, a2 = 0.f, a3 = 0.f;

    #pragma unroll 1
    for (int j = 0; j < NJ; ++j) {
        const int tbase = tg * TPT + j * NP;

        // ---- root level (wave-uniform addresses -> broadcast loads) ----
        int p[NP];
        #pragma unroll
        for (int k = 0; k < NP; ++k) {
            const int t  = tbase + k;
            const int rn = root_nodes[t];
            const float rbv = root_biases[t];
            p[k] = (x_s[xb | (rn ^ sz)] < rbv) ? 1 : 0;
        }

        // ---- levels 1..D: NP independent chains per level ----
        #pragma unroll
        for (int l = 1; l <= DD; ++l) {
            const int lbase = TT * ((1 << l) - 2);
            #pragma unroll
            for (int k = 0; k < NP; ++k) {
                const int t = tbase + k;
                const int e = lbase + (t << l) + p[k];
                const int   fi = nodes_flat[e];
                const float bi = biases_flat[e];
                const float ft = x_s[xb | (fi ^ sz)];
                p[k] = 2 * p[k] + ((ft < bi) ? 1 : 0);
            }
        }

        // ---- leaf gather (L2) + accumulate ----
        #pragma unroll
        for (int k = 0; k < NP; ++k) {
            const int t = tbase + k;
            const float4 lf = leaf4[(t << (DD + 1)) + p[k]];
            a0 += lf.x; a1 += lf.y; a2 += lf.z; a3 += lf.w;
        }
    }

    // ---- reduce 16 tree-group partials per sample (overlay on x_s) ----
    __syncthreads();
    ((float4*)x_s)[tid] = make_float4(a0, a1, a2, a3);  // 16 KB of the 64 KB
    __syncthreads();
    if (tid < S_ * 4) {                 // 256 threads: sample=tid>>2, comp=tid&3
        float o = 0.f;
        #pragma unroll
        for (int g = 0; g < NTG; ++g)
            o += x_s[(g << 8) + tid];   // addr = g*256 + tid: conflict-free
        out[(size_t)s0 * 4 + tid] = o;  // fully coalesced 1 KB store
    }
}

extern "C" void kernel_launch(void* const* d_in, const int* in_sizes, int n_in,
                              void* d_out, int out_size, void* d_ws, size_t ws_size,
                              hipStream_t stream) {
    const float* x           = (const float*)d_in[0];
    const int*   root_nodes  = (const int*)  d_in[1];
    const float* root_biases = (const float*)d_in[2];
    // d_in[3] = tree_indices = 2*t, folded into index math
    const int*   nodes_flat  = (const int*)  d_in[4];
    const float* biases_flat = (const float*)d_in[5];
    const float* leaf_nodes  = (const float*)d_in[6];
    float*       out         = (float*)d_out;

    constexpr size_t LDS_BYTES = (size_t)S_ * FF * sizeof(float);  // 65536
    tree_traverse_kernel<<<BB / S_, NT_, LDS_BYTES, stream>>>(
        x, root_nodes, root_biases, nodes_flat, biases_flat, leaf_nodes, out);
}

// Round 6
// 112.808 us; speedup vs baseline: 1.2137x; 1.2137x over previous
//
#include <hip/hip_runtime.h>
#include <hip/hip_fp16.h>

// B=16384 samples, F=256 features, T=512 trees, D=7 levels below root, C=4 outputs
#define BB 16384
#define FF 256
#define TT 512
#define DD 7

constexpr int S_   = 64;         // samples per block; one wave == one sample-group
constexpr int NT_  = 1024;       // 16 waves/block, grid=256 -> 1 block/CU
constexpr int NTG  = NT_ / S_;   // 16 tree-groups (one per wave)
constexpr int TPT  = TT / NTG;   // 32 trees per thread
constexpr int NP   = 8;          // concurrent tree chains per thread (proven R4)
constexpr int NJ   = TPT / NP;   // 4 outer iterations
constexpr int NPACK = TT * ((1 << (DD + 1)) - 2);  // 130048 internal nodes
constexpr int NPALL = NPACK + TT;                  // + packed roots
constexpr int NLEAF = TT << (DD + 1);              // 131072 leaf float4 rows

// Workspace layout: [int2 tp[NPALL]] [uint2 leafh[NLEAF]]
// tp: (feat, bias) packed -> ONE 8B gather per traversal step (R4: -20us vs two
// 4B gathers; divergent gathers pay TA cycles per line PER INSTRUCTION).
// leafh: leaf float4 packed to fp16x4 (8B) -> 8 leaves per 64B line instead of 4:
// expected distinct lines per 64-lane leaf gather drops ~41 -> ~28.
__global__ void pack_kernel(const int* __restrict__ nf,
                            const float* __restrict__ bf,
                            const int* __restrict__ rn,
                            const float* __restrict__ rb,
                            const float4* __restrict__ leaf4,
                            int2* __restrict__ tp,
                            uint2* __restrict__ leafh) {
    int i = blockIdx.x * 256 + threadIdx.x;
    if (i < NPACK) {
        tp[i] = make_int2(nf[i], __float_as_int(bf[i]));
    } else if (i < NPALL) {
        int t = i - NPACK;
        tp[i] = make_int2(rn[t], __float_as_int(rb[t]));
    } else if (i < NPALL + NLEAF) {
        int j = i - NPALL;
        const float4 lf = leaf4[j];
        __half2 h01 = __floats2half2_rn(lf.x, lf.y);
        __half2 h23 = __floats2half2_rn(lf.z, lf.w);
        uint2 w;
        w.x = *reinterpret_cast<unsigned int*>(&h01);
        w.y = *reinterpret_cast<unsigned int*>(&h23);
        leafh[j] = w;
    }
}

// Node-offset recurrence: with e_l = T*(2^l-2) + (t<<l) + p (the flat index into
// tp at level l), the update is e' = 2e + 2T + c  (c = compare bit), and the
// final leaf index is e_8 - NPACK. Cuts per-step address VALU to 2 ops.
// x rows live in LDS, XOR-swizzled (element f of row s at f ^ (s&31)) so
// bank = (f%32)^(s%32): shared-feature reads are conflict-free, no padding.
template<bool PACKED>
__global__ __launch_bounds__(NT_, 4)
void tree_traverse_kernel(const float* __restrict__ x,
                          const int*   __restrict__ root_nodes,
                          const float* __restrict__ root_biases,
                          const int*   __restrict__ nodes_flat,
                          const float* __restrict__ biases_flat,
                          const float* __restrict__ leaf_nodes,
                          const int2*  __restrict__ tp,
                          const uint2* __restrict__ leafh,
                          float*       __restrict__ out)
{
    extern __shared__ float x_s[];   // 64 rows * 256 floats = 64 KB

    const int tid = threadIdx.x;
    const int s   = tid & (S_ - 1);    // lane's sample (wave covers all 64)
    const int tg  = tid >> 6;          // tree-group == wave id
    const int s0  = blockIdx.x * S_;

    // ---- stage x rows: float4 global loads, swizzled scalar LDS stores ----
    {
        const float4* xg = (const float4*)(x + (size_t)s0 * FF);
        const int r  = tid >> 4;       // row 0..63
        const int v  = tid & 15;       // 16 of 64 float4 per row
        const int rz = r & 31;
        float* row = x_s + (r << 8);
        #pragma unroll
        for (int c = 0; c < 4; ++c) {
            const float4 q = xg[r * (FF / 4) + v + 16 * c];
            const int f0 = (v + 16 * c) * 4;
            row[(f0 + 0) ^ rz] = q.x;
            row[(f0 + 1) ^ rz] = q.y;
            row[(f0 + 2) ^ rz] = q.z;
            row[(f0 + 3) ^ rz] = q.w;
        }
    }
    __syncthreads();

    const int xb = s << 8;
    const int sz = s & 31;
    const float4* leaf4 = (const float4*)leaf_nodes;
    float a0 = 0.f, a1 = 0.f, a2 = 0.f, a3 = 0.f;

    #pragma unroll 1
    for (int j = 0; j < NJ; ++j) {
        const int tbase = tg * TPT + j * NP;

        // ---- root level (wave-uniform addresses -> scalar/broadcast loads) ----
        int e[NP];   // flat node offset, recurrence e' = 2e + 2T + c
        #pragma unroll
        for (int k = 0; k < NP; ++k) {
            const int t = tbase + k;
            int rn; float rbv;
            if (PACKED) {
                const int2 nb = tp[NPACK + t];
                rn = nb.x; rbv = __int_as_float(nb.y);
            } else {
                rn = root_nodes[t]; rbv = root_biases[t];
            }
            const int c = (x_s[xb | (rn ^ sz)] < rbv) ? 1 : 0;
            e[k] = 2 * t + c;                 // e at level 1 (lbase(1)=0)
        }

        // ---- levels 1..D: NP independent chains per level ----
        #pragma unroll
        for (int l = 1; l <= DD; ++l) {
            #pragma unroll
            for (int k = 0; k < NP; ++k) {
                int fi; float bi;
                if (PACKED) {
                    const int2 nb = tp[e[k]];
                    fi = nb.x; bi = __int_as_float(nb.y);
                } else {
                    fi = nodes_flat[e[k]]; bi = biases_flat[e[k]];
                }
                const float ft = x_s[xb | (fi ^ sz)];
                const int c = (ft < bi) ? 1 : 0;
                e[k] = 2 * e[k] + (2 * TT) + c;
            }
        }

        // ---- leaf gather (L2) + accumulate; leaf idx = e_8 - NPACK ----
        #pragma unroll
        for (int k = 0; k < NP; ++k) {
            const int li = e[k] - (254 * TT + 2 * TT);  // == e - NPACK - 2T? no:
            // e_8 = T*(2^8-2) + leafidx = 254*T + leafidx -> leafidx = e - 254*T
            const int leafidx = e[k] - 254 * TT;
            (void)li;
            if (PACKED) {
                const uint2 lw = leafh[leafidx];
                const __half2 h01 = *reinterpret_cast<const __half2*>(&lw.x);
                const __half2 h23 = *reinterpret_cast<const __half2*>(&lw.y);
                const float2 f01 = __half22float2(h01);
                const float2 f23 = __half22float2(h23);
                a0 += f01.x; a1 += f01.y; a2 += f23.x; a3 += f23.y;
            } else {
                const float4 lf = leaf4[leafidx];
                a0 += lf.x; a1 += lf.y; a2 += lf.z; a3 += lf.w;
            }
        }
    }

    // ---- reduce 16 tree-group partials per sample (overlay on x_s) ----
    __syncthreads();
    ((float4*)x_s)[tid] = make_float4(a0, a1, a2, a3);  // 16 KB of the 64 KB
    __syncthreads();
    if (tid < S_ * 4) {                 // 256 threads: sample=tid>>2, comp=tid&3
        float o = 0.f;
        #pragma unroll
        for (int g = 0; g < NTG; ++g)
            o += x_s[(g << 8) + tid];   // addr = g*256 + tid: conflict-free
        out[(size_t)s0 * 4 + tid] = o;  // fully coalesced 1 KB store
    }
}

extern "C" void kernel_launch(void* const* d_in, const int* in_sizes, int n_in,
                              void* d_out, int out_size, void* d_ws, size_t ws_size,
                              hipStream_t stream) {
    const float* x           = (const float*)d_in[0];
    const int*   root_nodes  = (const int*)  d_in[1];
    const float* root_biases = (const float*)d_in[2];
    // d_in[3] = tree_indices = 2*t, folded into index math
    const int*   nodes_flat  = (const int*)  d_in[4];
    const float* biases_flat = (const float*)d_in[5];
    const float* leaf_nodes  = (const float*)d_in[6];
    float*       out         = (float*)d_out;

    constexpr size_t LDS_BYTES = (size_t)S_ * FF * sizeof(float);       // 65536
    constexpr size_t WS_NEED   = (size_t)NPALL * 8 + (size_t)NLEAF * 8; // ~2.1 MB
    const bool packed = ws_size >= WS_NEED;
    int2*  tp    = (int2*)d_ws;
    uint2* leafh = (uint2*)((char*)d_ws + (size_t)NPALL * 8);

    if (packed) {
        constexpr int PACKN = NPALL + NLEAF;
        pack_kernel<<<(PACKN + 255) / 256, 256, 0, stream>>>(
            nodes_flat, biases_flat, root_nodes, root_biases,
            (const float4*)leaf_nodes, tp, leafh);
        tree_traverse_kernel<true><<<BB / S_, NT_, LDS_BYTES, stream>>>(
            x, root_nodes, root_biases, nodes_flat, biases_flat, leaf_nodes,
            tp, leafh, out);
    } else {
        tree_traverse_kernel<false><<<BB / S_, NT_, LDS_BYTES, stream>>>(
            x, root_nodes, root_biases, nodes_flat, biases_flat, leaf_nodes,
            tp, leafh, out);
    }
}

// Round 7
// 108.925 us; speedup vs baseline: 1.2570x; 1.0356x over previous
//
#include <hip/hip_runtime.h>

// B=16384 samples, F=256 features, T=512 trees, D=7 levels below root, C=4 outputs
#define BB 16384
#define FF 256
#define TT 512
#define DD 7

constexpr int S_  = 64;          // samples per block; one wave == one sample-group
constexpr int NT_ = 1024;        // 16 waves/block
constexpr int NTG = NT_ / S_;    // 16 tree-groups (one per wave)
constexpr int HT  = TT / 2;      // 256 trees per block (half split on blockIdx.y)
constexpr int TPT = HT / NTG;    // 16 trees per thread
constexpr int NP  = 8;           // concurrent tree chains (ILP)
constexpr int NJ  = TPT / NP;    // 2

// Two-level record tables (16B recs): levels (1,2) at R1, (3,4) at R3, (5,6) at R5,
// level 7 plain int2 at N7. F=256 so features pack into u8.
constexpr int NR1 = TT * 2;      // 1024
constexpr int NR3 = TT * 8;      // 4096
constexpr int NR5 = TT * 32;     // 16384
constexpr int NN7 = TT * 128;    // 65536
constexpr int NRECS = NR1 + NR3 + NR5 + NN7;

constexpr size_t OFF_R3   = (size_t)NR1 * 16;            //  16384
constexpr size_t OFF_R5   = OFF_R3 + (size_t)NR3 * 16;   //  81920
constexpr size_t OFF_N7   = OFF_R5 + (size_t)NR5 * 16;   // 344064
constexpr size_t OFF_PART = OFF_N7 + (size_t)NN7 * 8;    // 868352
constexpr size_t WS_NEED  = OFF_PART + (size_t)2 * BB * 4 * sizeof(float); // 1392640

__global__ void pack_kernel(const int* __restrict__ nf, const float* __restrict__ bf,
                            int4* __restrict__ R1, int4* __restrict__ R3,
                            int4* __restrict__ R5, int2* __restrict__ N7) {
    const int i = blockIdx.x * 256 + threadIdx.x;
    if (i < NR1) {                       // level1 node i, level2 children 2i,2i+1
        const int e0 = i, eC = 2 * TT + 2 * i;
        const int fp = (nf[e0] & 255) | ((nf[eC] & 255) << 8) | ((nf[eC + 1] & 255) << 16);
        R1[i] = make_int4(fp, __float_as_int(bf[e0]),
                          __float_as_int(bf[eC]), __float_as_int(bf[eC + 1]));
    } else if (i < NR1 + NR3) {
        const int r = i - NR1;
        const int e0 = 6 * TT + r, eC = 14 * TT + 2 * r;
        const int fp = (nf[e0] & 255) | ((nf[eC] & 255) << 8) | ((nf[eC + 1] & 255) << 16);
        R3[r] = make_int4(fp, __float_as_int(bf[e0]),
                          __float_as_int(bf[eC]), __float_as_int(bf[eC + 1]));
    } else if (i < NR1 + NR3 + NR5) {
        const int r = i - NR1 - NR3;
        const int e0 = 30 * TT + r, eC = 62 * TT + 2 * r;
        const int fp = (nf[e0] & 255) | ((nf[eC] & 255) << 8) | ((nf[eC + 1] & 255) << 16);
        R5[r] = make_int4(fp, __float_as_int(bf[e0]),
                          __float_as_int(bf[eC]), __float_as_int(bf[eC + 1]));
    } else if (i < NRECS) {
        const int r = i - NR1 - NR3 - NR5;
        const int e = 126 * TT + r;
        N7[r] = make_int2(nf[e], __float_as_int(bf[e]));
    }
}

// One record descends two levels: c0 from (f0,b0); both children compared
// speculatively (independent LDS reads), winner selected by c0.
__device__ __forceinline__ int step2(const int4 w, const int i,
                                     const float* __restrict__ x_s,
                                     const int xb, const int sz) {
    const float v0 = x_s[xb | ((w.x & 255) ^ sz)];
    const float vL = x_s[xb | (((w.x >> 8) & 255) ^ sz)];
    const float vR = x_s[xb | (((w.x >> 16) & 255) ^ sz)];
    const int   c0 = (v0 < __int_as_float(w.y)) ? 1 : 0;
    const float vc = c0 ? vR : vL;
    const float bc = c0 ? __int_as_float(w.w) : __int_as_float(w.z);
    const int   c1 = (vc < bc) ? 1 : 0;
    return 4 * i + 2 * c0 + c1;
}

// x rows in LDS, XOR-swizzled (element f of row s at f ^ (s&31)): bank =
// (f%32)^(s%32), so uniform-feature reads are conflict-free. Tree data gathered
// from L2; all 64 lanes of a wave share one tree, so gathers span few lines.
// grid=(256,2): 2 blocks/CU = 32 waves/CU; halves write partials to ws.
__global__ __launch_bounds__(NT_, 8)
void tree_traverse_kernel(const float* __restrict__ x,
                          const int*   __restrict__ root_nodes,
                          const float* __restrict__ root_biases,
                          const float4* __restrict__ leaf4,
                          const int4*  __restrict__ R1, const int4* __restrict__ R3,
                          const int4*  __restrict__ R5, const int2* __restrict__ N7,
                          float*       __restrict__ part)
{
    extern __shared__ float x_s[];   // 64 rows * 256 floats = 64 KB

    const int tid = threadIdx.x;
    const int s   = tid & (S_ - 1);
    const int tg  = tid >> 6;
    const int s0  = blockIdx.x * S_;
    const int h0  = blockIdx.y * HT;

    // ---- stage x rows: float4 global loads, swizzled scalar LDS stores ----
    {
        const float4* xg = (const float4*)(x + (size_t)s0 * FF);
        const int r  = tid >> 4;
        const int v  = tid & 15;
        const int rz = r & 31;
        float* row = x_s + (r << 8);
        #pragma unroll
        for (int c = 0; c < 4; ++c) {
            const float4 q = xg[r * (FF / 4) + v + 16 * c];
            const int f0 = (v + 16 * c) * 4;
            row[(f0 + 0) ^ rz] = q.x;
            row[(f0 + 1) ^ rz] = q.y;
            row[(f0 + 2) ^ rz] = q.z;
            row[(f0 + 3) ^ rz] = q.w;
        }
    }
    __syncthreads();

    const int xb = s << 8;
    const int sz = s & 31;
    float a0 = 0.f, a1 = 0.f, a2 = 0.f, a3 = 0.f;

    #pragma unroll 1
    for (int j = 0; j < NJ; ++j) {
        const int tbase = h0 + tg * TPT + j * NP;
        int p[NP];

        // ---- root (wave-uniform -> scalar loads) ----
        #pragma unroll
        for (int k = 0; k < NP; ++k) {
            const int t = tbase + k;
            p[k] = (x_s[xb | (root_nodes[t] ^ sz)] < root_biases[t]) ? 1 : 0;
        }
        // ---- levels 1+2 ----
        #pragma unroll
        for (int k = 0; k < NP; ++k)
            p[k] = step2(R1[((tbase + k) << 1) + p[k]], p[k], x_s, xb, sz);
        // ---- levels 3+4 ----
        #pragma unroll
        for (int k = 0; k < NP; ++k)
            p[k] = step2(R3[((tbase + k) << 3) + p[k]], p[k], x_s, xb, sz);
        // ---- levels 5+6 ----
        #pragma unroll
        for (int k = 0; k < NP; ++k)
            p[k] = step2(R5[((tbase + k) << 5) + p[k]], p[k], x_s, xb, sz);
        // ---- level 7 ----
        #pragma unroll
        for (int k = 0; k < NP; ++k) {
            const int2 n = N7[((tbase + k) << 7) + p[k]];
            const int c = (x_s[xb | ((n.x & 255) ^ sz)] < __int_as_float(n.y)) ? 1 : 0;
            p[k] = 2 * p[k] + c;
        }
        // ---- leaf gather (fp32, off critical path) + accumulate ----
        #pragma unroll
        for (int k = 0; k < NP; ++k) {
            const float4 lf = leaf4[((tbase + k) << 8) + p[k]];
            a0 += lf.x; a1 += lf.y; a2 += lf.z; a3 += lf.w;
        }
    }

    // ---- reduce 16 wave partials per sample (overlay on x_s), write half-partial ----
    __syncthreads();
    ((float4*)x_s)[tid] = make_float4(a0, a1, a2, a3);
    __syncthreads();
    if (tid < S_ * 4) {
        float o = 0.f;
        #pragma unroll
        for (int g = 0; g < NTG; ++g)
            o += x_s[(g << 8) + tid];
        part[((size_t)blockIdx.y * BB + s0) * 4 + tid] = o;   // coalesced 1 KB
    }
}

__global__ void sum_kernel(const float4* __restrict__ part, float4* __restrict__ out) {
    const int i = blockIdx.x * 256 + threadIdx.x;
    if (i < BB) {
        const float4 a = part[i], b = part[BB + i];
        out[i] = make_float4(a.x + b.x, a.y + b.y, a.z + b.z, a.w + b.w);
    }
}

// Fallback (ws too small): R5-style direct traversal, single half, known-correct.
__global__ __launch_bounds__(NT_, 4)
void tree_traverse_fallback(const float* __restrict__ x,
                            const int* __restrict__ root_nodes,
                            const float* __restrict__ root_biases,
                            const int* __restrict__ nodes_flat,
                            const float* __restrict__ biases_flat,
                            const float* __restrict__ leaf_nodes,
                            float* __restrict__ out)
{
    extern __shared__ float x_s[];
    const int tid = threadIdx.x;
    const int s = tid & (S_ - 1), tg = tid >> 6;
    const int s0 = blockIdx.x * S_;
    {
        const float4* xg = (const float4*)(x + (size_t)s0 * FF);
        const int r = tid >> 4, v = tid & 15, rz = r & 31;
        float* row = x_s + (r << 8);
        #pragma unroll
        for (int c = 0; c < 4; ++c) {
            const float4 q = xg[r * (FF / 4) + v + 16 * c];
            const int f0 = (v + 16 * c) * 4;
            row[(f0 + 0) ^ rz] = q.x; row[(f0 + 1) ^ rz] = q.y;
            row[(f0 + 2) ^ rz] = q.z; row[(f0 + 3) ^ rz] = q.w;
        }
    }
    __syncthreads();
    const int xb = s << 8, sz = s & 31;
    const float4* leaf4 = (const float4*)leaf_nodes;
    float a0 = 0.f, a1 = 0.f, a2 = 0.f, a3 = 0.f;
    #pragma unroll 1
    for (int j = 0; j < TT / NTG / NP; ++j) {
        const int tbase = tg * (TT / NTG) + j * NP;
        int p[NP];
        #pragma unroll
        for (int k = 0; k < NP; ++k) {
            const int t = tbase + k;
            p[k] = 2 * t + ((x_s[xb | (root_nodes[t] ^ sz)] < root_biases[t]) ? 1 : 0);
        }
        #pragma unroll
        for (int l = 1; l <= DD; ++l) {
            #pragma unroll
            for (int k = 0; k < NP; ++k) {
                const int fi = nodes_flat[p[k]];
                const float bi = biases_flat[p[k]];
                const int c = (x_s[xb | (fi ^ sz)] < bi) ? 1 : 0;
                p[k] = 2 * p[k] + 2 * TT + c;
            }
        }
        #pragma unroll
        for (int k = 0; k < NP; ++k) {
            const float4 lf = leaf4[p[k] - 254 * TT];
            a0 += lf.x; a1 += lf.y; a2 += lf.z; a3 += lf.w;
        }
    }
    __syncthreads();
    ((float4*)x_s)[tid] = make_float4(a0, a1, a2, a3);
    __syncthreads();
    if (tid < S_ * 4) {
        float o = 0.f;
        #pragma unroll
        for (int g = 0; g < NTG; ++g) o += x_s[(g << 8) + tid];
        out[(size_t)s0 * 4 + tid] = o;
    }
}

extern "C" void kernel_launch(void* const* d_in, const int* in_sizes, int n_in,
                              void* d_out, int out_size, void* d_ws, size_t ws_size,
                              hipStream_t stream) {
    const float* x           = (const float*)d_in[0];
    const int*   root_nodes  = (const int*)  d_in[1];
    const float* root_biases = (const float*)d_in[2];
    // d_in[3] = tree_indices = 2*t, folded into index math
    const int*   nodes_flat  = (const int*)  d_in[4];
    const float* biases_flat = (const float*)d_in[5];
    const float* leaf_nodes  = (const float*)d_in[6];
    float*       out         = (float*)d_out;

    constexpr size_t LDS_BYTES = (size_t)S_ * FF * sizeof(float);  // 65536

    if (ws_size >= WS_NEED) {
        char* ws = (char*)d_ws;
        int4* R1 = (int4*)ws;
        int4* R3 = (int4*)(ws + OFF_R3);
        int4* R5 = (int4*)(ws + OFF_R5);
        int2* N7 = (int2*)(ws + OFF_N7);
        float* part = (float*)(ws + OFF_PART);

        pack_kernel<<<(NRECS + 255) / 256, 256, 0, stream>>>(
            nodes_flat, biases_flat, R1, R3, R5, N7);
        dim3 grid(BB / S_, 2);
        tree_traverse_kernel<<<grid, NT_, LDS_BYTES, stream>>>(
            x, root_nodes, root_biases, (const float4*)leaf_nodes,
            R1, R3, R5, N7, part);
        sum_kernel<<<BB / 256, 256, 0, stream>>>((const float4*)part, (float4*)out);
    } else {
        tree_traverse_fallback<<<BB / S_, NT_, LDS_BYTES, stream>>>(
            x, root_nodes, root_biases, nodes_flat, biases_flat, leaf_nodes, out);
    }
}

// Round 8
// 102.807 us; speedup vs baseline: 1.3318x; 1.0595x over previous
//
#include <hip/hip_runtime.h>
#include <hip/hip_fp16.h>

// B=16384 samples, F=256 features, T=512 trees, D=7 levels below root, C=4 outputs
#define BB 16384
#define FF 256
#define TT 512
#define DD 7

constexpr int S_  = 64;          // samples per block; one wave == one sample-group
constexpr int NT_ = 1024;        // 16 waves/block
constexpr int NTG = NT_ / S_;    // 16 tree-groups (one per wave)
constexpr int HT  = TT / 2;      // 256 trees per block (half split on blockIdx.y)
constexpr int TPT = HT / NTG;    // 16 trees per thread
constexpr int NP  = 8;           // concurrent tree chains (ILP)
constexpr int NJ  = TPT / NP;    // 2

// Tables: R1 covers levels (1,2), R3 (3,4), R5 (5,6) as 16B two-level records;
// N7 = level-7 (feat,bias); LP = fp16x4 leaf PAIRS (16B) indexed by p7 so the
// leaf data arrives in the same dependent round as N7.
constexpr int NR1 = TT * 2;      // 1024
constexpr int NR3 = TT * 8;      // 4096
constexpr int NR5 = TT * 32;     // 16384
constexpr int NN7 = TT * 128;    // 65536 (also LP count)
constexpr int NTOT = NR1 + NR3 + NR5 + NN7 + NN7;

constexpr size_t OFF_R3   = (size_t)NR1 * 16;
constexpr size_t OFF_R5   = OFF_R3 + (size_t)NR3 * 16;
constexpr size_t OFF_N7   = OFF_R5 + (size_t)NR5 * 16;
constexpr size_t OFF_LP   = OFF_N7 + (size_t)NN7 * 8;
constexpr size_t OFF_PART = OFF_LP + (size_t)NN7 * 16;
constexpr size_t WS_NEED  = OFF_PART + (size_t)2 * BB * 4 * sizeof(float);

__global__ void pack_kernel(const int* __restrict__ nf, const float* __restrict__ bf,
                            const float4* __restrict__ leaf4,
                            int4* __restrict__ R1, int4* __restrict__ R3,
                            int4* __restrict__ R5, int2* __restrict__ N7,
                            uint4* __restrict__ LP) {
    const int i = blockIdx.x * 256 + threadIdx.x;
    if (i < NR1) {                       // level-1 node i; level-2 children 2i,2i+1
        const int e0 = i, eC = 2 * TT + 2 * i;
        const int fp = (nf[e0] & 255) | ((nf[eC] & 255) << 8) | ((nf[eC + 1] & 255) << 16);
        R1[i] = make_int4(fp, __float_as_int(bf[e0]),
                          __float_as_int(bf[eC]), __float_as_int(bf[eC + 1]));
    } else if (i < NR1 + NR3) {
        const int r = i - NR1;
        const int e0 = 6 * TT + r, eC = 14 * TT + 2 * r;
        const int fp = (nf[e0] & 255) | ((nf[eC] & 255) << 8) | ((nf[eC + 1] & 255) << 16);
        R3[r] = make_int4(fp, __float_as_int(bf[e0]),
                          __float_as_int(bf[eC]), __float_as_int(bf[eC + 1]));
    } else if (i < NR1 + NR3 + NR5) {
        const int r = i - NR1 - NR3;
        const int e0 = 30 * TT + r, eC = 62 * TT + 2 * r;
        const int fp = (nf[e0] & 255) | ((nf[eC] & 255) << 8) | ((nf[eC + 1] & 255) << 16);
        R5[r] = make_int4(fp, __float_as_int(bf[e0]),
                          __float_as_int(bf[eC]), __float_as_int(bf[eC + 1]));
    } else if (i < NR1 + NR3 + NR5 + NN7) {
        const int r = i - NR1 - NR3 - NR5;
        const int e = 126 * TT + r;
        N7[r] = make_int2(nf[e] & 255, __float_as_int(bf[e]));
    } else if (i < NTOT) {
        const int j = i - NR1 - NR3 - NR5 - NN7;   // leaf-pair id: leaves 2j, 2j+1
        const float4 l0 = leaf4[2 * j], l1 = leaf4[2 * j + 1];
        const __half2 a = __floats2half2_rn(l0.x, l0.y), b = __floats2half2_rn(l0.z, l0.w);
        const __half2 c = __floats2half2_rn(l1.x, l1.y), d = __floats2half2_rn(l1.z, l1.w);
        uint4 w;
        w.x = *reinterpret_cast<const unsigned int*>(&a);
        w.y = *reinterpret_cast<const unsigned int*>(&b);
        w.z = *reinterpret_cast<const unsigned int*>(&c);
        w.w = *reinterpret_cast<const unsigned int*>(&d);
        LP[j] = w;
    }
}

// Two-level step: rec w covers node i at level l and its two children; returns
// index at level l+2. Child compares are speculative (independent LDS reads).
__device__ __forceinline__ int step2(const int4 w, const int i,
                                     const float* __restrict__ x_s,
                                     const int xb, const int sz) {
    const float v0 = x_s[xb | ((w.x & 255) ^ sz)];
    const float vL = x_s[xb | (((w.x >> 8) & 255) ^ sz)];
    const float vR = x_s[xb | (((w.x >> 16) & 255) ^ sz)];
    const int   c0 = (v0 < __int_as_float(w.y)) ? 1 : 0;
    const float vc = c0 ? vR : vL;
    const float bc = c0 ? __int_as_float(w.w) : __int_as_float(w.z);
    const int   c1 = (vc < bc) ? 1 : 0;
    return 4 * i + 2 * c0 + c1;
}

// x rows in LDS, XOR-swizzled (element f of row s at f ^ (s&31)): bank =
// (f%32)^(s%32) -> uniform-feature reads conflict-free. Root + R1 are loaded
// via readfirstlane-certified wave-uniform addresses (s_load, constant cache,
// zero dependencies). Vector L2 rounds per chain: R3 -> R5 -> {N7 + LP}.
__global__ __launch_bounds__(NT_, 8)
void tree_traverse_kernel(const float* __restrict__ x,
                          const int*   __restrict__ root_nodes,
                          const float* __restrict__ root_biases,
                          const int4*  __restrict__ R1, const int4* __restrict__ R3,
                          const int4*  __restrict__ R5, const int2* __restrict__ N7,
                          const uint4* __restrict__ LP,
                          float*       __restrict__ part)
{
    extern __shared__ float x_s[];   // 64 rows * 256 floats = 64 KB

    const int tid = threadIdx.x;
    const int s   = tid & (S_ - 1);
    const int tg  = tid >> 6;
    const int s0  = blockIdx.x * S_;
    const int h0  = blockIdx.y * HT;

    // ---- stage x rows: float4 global loads, swizzled scalar LDS stores ----
    {
        const float4* xg = (const float4*)(x + (size_t)s0 * FF);
        const int r  = tid >> 4;
        const int v  = tid & 15;
        const int rz = r & 31;
        float* row = x_s + (r << 8);
        #pragma unroll
        for (int c = 0; c < 4; ++c) {
            const float4 q = xg[r * (FF / 4) + v + 16 * c];
            const int f0 = (v + 16 * c) * 4;
            row[(f0 + 0) ^ rz] = q.x;
            row[(f0 + 1) ^ rz] = q.y;
            row[(f0 + 2) ^ rz] = q.z;
            row[(f0 + 3) ^ rz] = q.w;
        }
    }
    __syncthreads();

    const int xb = s << 8;
    const int sz = s & 31;
    float a0 = 0.f, a1 = 0.f, a2 = 0.f, a3 = 0.f;

    #pragma unroll 1
    for (int j = 0; j < NJ; ++j) {
        const int tbase = h0 + tg * TPT + j * NP;
        int p[NP];

        // ---- root + levels 1,2: scalar loads (wave-uniform), per-lane select ----
        #pragma unroll
        for (int k = 0; k < NP; ++k) {
            const int tu = __builtin_amdgcn_readfirstlane(tbase + k);
            const int   rn  = root_nodes[tu];        // s_load
            const float rbv = root_biases[tu];       // s_load
            const int4  rA  = R1[2 * tu];            // s_load_dwordx4
            const int4  rB  = R1[2 * tu + 1];        // s_load_dwordx4
            const int c0 = (x_s[xb | (rn ^ sz)] < rbv) ? 1 : 0;
            int4 r;                                   // per-lane select of 16B rec
            r.x = c0 ? rB.x : rA.x;  r.y = c0 ? rB.y : rA.y;
            r.z = c0 ? rB.z : rA.z;  r.w = c0 ? rB.w : rA.w;
            p[k] = step2(r, c0, x_s, xb, sz);        // -> level-3 index [0,8)
        }
        // ---- levels 3+4 (L2 round 1) ----
        #pragma unroll
        for (int k = 0; k < NP; ++k)
            p[k] = step2(R3[((tbase + k) << 3) + p[k]], p[k], x_s, xb, sz);
        // ---- levels 5+6 (L2 round 2) ----
        #pragma unroll
        for (int k = 0; k < NP; ++k)
            p[k] = step2(R5[((tbase + k) << 5) + p[k]], p[k], x_s, xb, sz);
        // ---- level 7 + leaf pair (L2 round 3: two independent gathers) ----
        #pragma unroll
        for (int k = 0; k < NP; ++k) {
            const int idx7 = ((tbase + k) << 7) + p[k];
            const int2  n  = N7[idx7];
            const uint4 lp = LP[idx7];
            const int c7 = (x_s[xb | (n.x ^ sz)] < __int_as_float(n.y)) ? 1 : 0;
            const unsigned int w01 = c7 ? lp.z : lp.x;
            const unsigned int w23 = c7 ? lp.w : lp.y;
            const float2 f01 = __half22float2(*reinterpret_cast<const __half2*>(&w01));
            const float2 f23 = __half22float2(*reinterpret_cast<const __half2*>(&w23));
            a0 += f01.x; a1 += f01.y; a2 += f23.x; a3 += f23.y;
        }
    }

    // ---- reduce 16 wave partials per sample (overlay on x_s), write half-partial ----
    __syncthreads();
    ((float4*)x_s)[tid] = make_float4(a0, a1, a2, a3);
    __syncthreads();
    if (tid < S_ * 4) {
        float o = 0.f;
        #pragma unroll
        for (int g = 0; g < NTG; ++g)
            o += x_s[(g << 8) + tid];
        part[((size_t)blockIdx.y * BB + s0) * 4 + tid] = o;   // coalesced 1 KB
    }
}

__global__ void sum_kernel(const float4* __restrict__ part, float4* __restrict__ out) {
    const int i = blockIdx.x * 256 + threadIdx.x;
    if (i < BB) {
        const float4 a = part[i], b = part[BB + i];
        out[i] = make_float4(a.x + b.x, a.y + b.y, a.z + b.z, a.w + b.w);
    }
}

// Fallback (ws too small): direct traversal, known-correct.
__global__ __launch_bounds__(NT_, 4)
void tree_traverse_fallback(const float* __restrict__ x,
                            const int* __restrict__ root_nodes,
                            const float* __restrict__ root_biases,
                            const int* __restrict__ nodes_flat,
                            const float* __restrict__ biases_flat,
                            const float* __restrict__ leaf_nodes,
                            float* __restrict__ out)
{
    extern __shared__ float x_s[];
    const int tid = threadIdx.x;
    const int s = tid & (S_ - 1), tg = tid >> 6;
    const int s0 = blockIdx.x * S_;
    {
        const float4* xg = (const float4*)(x + (size_t)s0 * FF);
        const int r = tid >> 4, v = tid & 15, rz = r & 31;
        float* row = x_s + (r << 8);
        #pragma unroll
        for (int c = 0; c < 4; ++c) {
            const float4 q = xg[r * (FF / 4) + v + 16 * c];
            const int f0 = (v + 16 * c) * 4;
            row[(f0 + 0) ^ rz] = q.x; row[(f0 + 1) ^ rz] = q.y;
            row[(f0 + 2) ^ rz] = q.z; row[(f0 + 3) ^ rz] = q.w;
        }
    }
    __syncthreads();
    const int xb = s << 8, sz = s & 31;
    const float4* leaf4 = (const float4*)leaf_nodes;
    float a0 = 0.f, a1 = 0.f, a2 = 0.f, a3 = 0.f;
    #pragma unroll 1
    for (int j = 0; j < TT / NTG / NP; ++j) {
        const int tbase = tg * (TT / NTG) + j * NP;
        int p[NP];
        #pragma unroll
        for (int k = 0; k < NP; ++k) {
            const int t = tbase + k;
            p[k] = 2 * t + ((x_s[xb | (root_nodes[t] ^ sz)] < root_biases[t]) ? 1 : 0);
        }
        #pragma unroll
        for (int l = 1; l <= DD; ++l) {
            #pragma unroll
            for (int k = 0; k < NP; ++k) {
                const int fi = nodes_flat[p[k]];
                const float bi = biases_flat[p[k]];
                const int c = (x_s[xb | (fi ^ sz)] < bi) ? 1 : 0;
                p[k] = 2 * p[k] + 2 * TT + c;
            }
        }
        #pragma unroll
        for (int k = 0; k < NP; ++k) {
            const float4 lf = leaf4[p[k] - 254 * TT];
            a0 += lf.x; a1 += lf.y; a2 += lf.z; a3 += lf.w;
        }
    }
    __syncthreads();
    ((float4*)x_s)[tid] = make_float4(a0, a1, a2, a3);
    __syncthreads();
    if (tid < S_ * 4) {
        float o = 0.f;
        #pragma unroll
        for (int g = 0; g < NTG; ++g) o += x_s[(g << 8) + tid];
        out[(size_t)s0 * 4 + tid] = o;
    }
}

extern "C" void kernel_launch(void* const* d_in, const int* in_sizes, int n_in,
                              void* d_out, int out_size, void* d_ws, size_t ws_size,
                              hipStream_t stream) {
    const float* x           = (const float*)d_in[0];
    const int*   root_nodes  = (const int*)  d_in[1];
    const float* root_biases = (const float*)d_in[2];
    // d_in[3] = tree_indices = 2*t, folded into index math
    const int*   nodes_flat  = (const int*)  d_in[4];
    const float* biases_flat = (const float*)d_in[5];
    const float* leaf_nodes  = (const float*)d_in[6];
    float*       out         = (float*)d_out;

    constexpr size_t LDS_BYTES = (size_t)S_ * FF * sizeof(float);  // 65536

    if (ws_size >= WS_NEED) {
        char* ws = (char*)d_ws;
        int4*  R1 = (int4*)ws;
        int4*  R3 = (int4*)(ws + OFF_R3);
        int4*  R5 = (int4*)(ws + OFF_R5);
        int2*  N7 = (int2*)(ws + OFF_N7);
        uint4* LP = (uint4*)(ws + OFF_LP);
        float* part = (float*)(ws + OFF_PART);

        pack_kernel<<<(NTOT + 255) / 256, 256, 0, stream>>>(
            nodes_flat, biases_flat, (const float4*)leaf_nodes, R1, R3, R5, N7, LP);
        dim3 grid(BB / S_, 2);
        tree_traverse_kernel<<<grid, NT_, LDS_BYTES, stream>>>(
            x, root_nodes, root_biases, R1, R3, R5, N7, LP, part);
        sum_kernel<<<BB / 256, 256, 0, stream>>>((const float4*)part, (float4*)out);
    } else {
        tree_traverse_fallback<<<BB / S_, NT_, LDS_BYTES, stream>>>(
            x, root_nodes, root_biases, nodes_flat, biases_flat, leaf_nodes, out);
    }
}